// Round 8
// baseline (138.137 us; speedup 1.0000x reference)
//
#include <hip/hip_runtime.h>

// ST-GCN fused block for MI355X (gfx950).  FP32 I/O, bf16 at MFMA boundaries.
// 3 dispatches: kwin(+prep) -> kmain(+BN-stats, 128-way replicated atomics)
//               -> kapply(stats reduce + BN + ReLU + residual, pure streaming).
// xs layout: [n][l][25 v][64 ci] bf16 (unpadded; kmain zeroes v=25..31 rows).
// zb layout: [n][c][l][w] bf16  == out's [n][c][l][v] -> kapply is layout-free.
// statsbuf: 128 copies x 128 f32 (sum[64], sumsq[64]) -> 16 atomics/address.

typedef unsigned short ushort_t;
typedef __attribute__((ext_vector_type(8))) short short8;   // 8 x bf16 MFMA frag
typedef __attribute__((ext_vector_type(4))) float f32x4;
typedef __attribute__((ext_vector_type(8))) unsigned short us8;

#define N_  4
#define CI_ 64
#define CO_ 64
#define L_  1024
#define V_  25
#define P_  3
#define KS_ 9
#define NLV 102400.0f   // N_*L_*V_  (BN population count per channel)
#define NREP 128        // stats replication factor

__device__ __forceinline__ float b2f(ushort_t u) {
  union { float f; unsigned int i; } c; c.i = ((unsigned int)u) << 16; return c.f;
}
__device__ __forceinline__ ushort_t f2b(float f) {
  union { float f; unsigned int i; } c; c.f = f;
  unsigned int u = c.i;
  u += 0x7fffu + ((u >> 16) & 1u);      // round-to-nearest-even
  return (ushort_t)(u >> 16);
}

// ---------------------------------------------------------------------------
// kwin: causal 9-wide window-sum along l, fp32 x -> bf16 xs[n][l][25*64].
// block = (chunk of 8 l's, n); chunk==128 & n==0 does prep instead.
// Sliding-window: each thread owns (v,ci) columns; 8 outputs per column via
// running sum (23 LDS reads/column vs 72 for direct 9-tap).
__global__ __launch_bounds__(256) void kwin(
    const float* __restrict__ x, ushort_t* __restrict__ xs,
    const float* __restrict__ A, const float* __restrict__ E,
    const float* __restrict__ cb, const float* __restrict__ W,
    ushort_t* __restrict__ a2raw, float* __restrict__ biastab,
    ushort_t* __restrict__ wb, float* __restrict__ statsbuf)
{
  const int chunk = blockIdx.x;                 // 0..128
  const int n = blockIdx.y;
  const int tid = threadIdx.x;

  if (chunk == 128) {                           // ---- prep block ----
    if (n != 0) return;
    __shared__ float colA[P_ * 32];
    if (tid < P_ * 32) {
      int p = tid >> 5, w = tid & 31;
      float s = 0.f;
      if (w < V_)
        for (int v = 0; v < V_; ++v) {
          int idx = (p * V_ + v) * V_ + w;
          s += A[idx] * E[idx];
        }
      colA[tid] = s;
    }
    for (int e = tid; e < 32 * 96; e += 256) {
      int w = e / 96, k = e - w * 96;
      int p = k >> 5, v = k & 31;
      float val = 0.f;
      if (w < V_ && v < V_) {
        int idx = (p * V_ + v) * V_ + w;
        val = A[idx] * E[idx];
      }
      a2raw[e] = f2b(val);
    }
    for (int e = tid; e < 192 * 64; e += 256) wb[e] = f2b(W[e]);
    __syncthreads();
    for (int e = tid; e < 32 * 64; e += 256) {
      int w = e >> 6, c = e & 63;
      float s = 0.f;
      for (int p = 0; p < P_; ++p) s += cb[p * 64 + c] * colA[p * 32 + w];
      biastab[e] = s;
    }
    for (int e = tid; e < NREP * 128; e += 256) statsbuf[e] = 0.f;
    return;
  }

  // ---- window block ----
  __shared__ ushort_t tile[64 * 402];           // 51.5 KB; stride 402 (odd dword)
  const int l0 = chunk * 8;
  const long xn = (long)n * CI_ * L_ * V_;
  for (int m = tid; m < 6400; m += 256) {       // 64 ci x 400 f32 -> bf16
    int ci = m / 100;
    int j4 = (m - ci * 100) * 4;                // 0..396
    f32x4 d;
    if (chunk == 0 && j4 < 200) {
      d = (f32x4){0.f, 0.f, 0.f, 0.f};          // l < 0 halo (li 0..7)
    } else {
      d = *(const f32x4*)(x + xn + (long)ci * (L_ * V_) + (l0 - 8) * V_ + j4);
    }
    ushort_t* dst = &tile[ci * 402 + j4];
    dst[0] = f2b(d[0]); dst[1] = f2b(d[1]); dst[2] = f2b(d[2]); dst[3] = f2b(d[3]);
  }
  __syncthreads();
  // sliding window per (v,ci) column; cid = v*64+ci, consecutive lanes ->
  // consecutive cid -> coalesced b16 stores per l_.
  const long xsbase = ((long)n * L_ + l0) * 1600;
  for (int cid = tid; cid < 1600; cid += 256) {
    const int v = cid >> 6, ci = cid & 63;
    const ushort_t* col = &tile[ci * 402 + v];  // + li*25 steps along l
    float s = 0.f;
#pragma unroll
    for (int li = 0; li < 9; ++li) s += b2f(col[li * 25]);
    xs[xsbase + cid] = f2b(s);                  // l_ = 0 (li window 0..8)
#pragma unroll
    for (int l_ = 1; l_ < 8; ++l_) {
      s += b2f(col[(l_ + 8) * 25]) - b2f(col[(l_ - 1) * 25]);
      xs[xsbase + l_ * 1600 + cid] = f2b(s);
    }
  }
}

// ---------------------------------------------------------------------------
// kmain: per-(n, 2 l's) block.
//   stage1: t1[k=192][2l x 32v] = Wb[192x64] @ Xs[64 x 64cols]
//   stage2: z[c=64][w=32] per l = T1c[64x96] @ A2[96x32]; + cnt(l)*bias
//   epilogue: store zb[n][c][l][w] (out-layout) + BN stats atomics.
__global__ __launch_bounds__(256) void kmain(
    const ushort_t* __restrict__ xs,      // [n][l][1600] bf16
    const ushort_t* __restrict__ Wb,      // [192][64] bf16 (L1-hot)
    const ushort_t* __restrict__ a2,      // [32 w][96 k] bf16 (L1-hot)
    const float*    __restrict__ biastab, // [32 w][64 c] f32 (L1-hot)
    ushort_t*       __restrict__ zb,
    float*          __restrict__ statsbuf)
{
  const int lb = blockIdx.x;            // 2 l's per block
  const int n  = blockIdx.y;
  const int tid = threadIdx.x, lane = tid & 63, wv = tid >> 6;
  const int m16 = lane & 15, quad = lane >> 4;

  __shared__ __align__(16) ushort_t XT[2 * 32 * 72];   // [l_][v][ci], stride 72
  __shared__ __align__(16) ushort_t T1[2 * 64 * 104];  // [l_][c][K=96]

  // stage XT: 3200 contiguous bf16 -> 400 us8 chunks; zero pad rows v=25..31
  {
    const ushort_t* src = xs + ((long)n * L_ + 2 * lb) * 1600;
    for (int m = tid; m < 400; m += 256) {
      int l_ = m / 200, mr = m - l_ * 200;
      int v = mr >> 3, sub = mr & 7;
      *(us8*)(&XT[l_ * 2304 + v * 72 + sub * 8]) = *(const us8*)(src + m * 8);
    }
    if (tid < 126) {                    // 2 l_ x 63 us8 = pad rows 25..31
      int l_ = tid / 63, j = tid - l_ * 63;
      *(us8*)(&XT[l_ * 2304 + 1800 + j * 8]) = (us8){0,0,0,0,0,0,0,0};
    }
  }
  __syncthreads();

  // ---- stage 1: 24 MFMA per wave (3 mt x 4 nt x 2 ks) ----
  short8 bfr[4][2];
#pragma unroll
  for (int nt = 0; nt < 4; ++nt)
#pragma unroll
    for (int ks = 0; ks < 2; ++ks)
      bfr[nt][ks] = *(const short8*)(
          &XT[(nt >> 1) * 2304 + ((nt & 1) * 16 + m16) * 72 + ks * 32 + quad * 8]);

  f32x4 acc1[3][4];
#pragma unroll
  for (int i = 0; i < 3; ++i)
#pragma unroll
    for (int j = 0; j < 4; ++j) acc1[i][j] = (f32x4){0.f, 0.f, 0.f, 0.f};

#pragma unroll
  for (int i = 0; i < 3; ++i) {
    const int mt = wv * 3 + i;
    const ushort_t* wrow = Wb + (mt * 16 + m16) * 64 + quad * 8;
    short8 af0 = *(const short8*)(wrow);
    short8 af1 = *(const short8*)(wrow + 32);
#pragma unroll
    for (int nt = 0; nt < 4; ++nt) {
      acc1[i][nt] = __builtin_amdgcn_mfma_f32_16x16x32_bf16(af0, bfr[nt][0], acc1[i][nt], 0, 0, 0);
      acc1[i][nt] = __builtin_amdgcn_mfma_f32_16x16x32_bf16(af1, bfr[nt][1], acc1[i][nt], 0, 0, 0);
    }
  }
  // repack t1 -> T1[l_][c][p*32+v]  (D: row = quad*4+r, col = m16)
#pragma unroll
  for (int i = 0; i < 3; ++i) {
    const int mt = wv * 3 + i;
#pragma unroll
    for (int nt = 0; nt < 4; ++nt) {
      const int l_ = nt >> 1;
      const int col = (nt & 1) * 16 + m16;
#pragma unroll
      for (int r = 0; r < 4; ++r) {
        int k = mt * 16 + quad * 4 + r;          // k = p*64 + c
        T1[l_ * 6656 + (k & 63) * 104 + (k >> 6) * 32 + col] = f2b(acc1[i][nt][r]);
      }
    }
  }
  __syncthreads();

  // ---- stage 2: 12 MFMA per wave; B-frags direct from global a2 (L1-hot) ----
  short8 bfr2[2][3];
#pragma unroll
  for (int nt = 0; nt < 2; ++nt)
#pragma unroll
    for (int ks = 0; ks < 3; ++ks)
      bfr2[nt][ks] = *(const short8*)(a2 + (nt * 16 + m16) * 96 + ks * 32 + quad * 8);

  f32x4 acc2[2][2];
#pragma unroll
  for (int l_ = 0; l_ < 2; ++l_)
#pragma unroll
    for (int nt = 0; nt < 2; ++nt) acc2[l_][nt] = (f32x4){0.f, 0.f, 0.f, 0.f};

#pragma unroll
  for (int l_ = 0; l_ < 2; ++l_) {
#pragma unroll
    for (int ks = 0; ks < 3; ++ks) {
      short8 af = *(const short8*)(&T1[l_ * 6656 + (wv * 16 + m16) * 104 + ks * 32 + quad * 8]);
      acc2[l_][0] = __builtin_amdgcn_mfma_f32_16x16x32_bf16(af, bfr2[0][ks], acc2[l_][0], 0, 0, 0);
      acc2[l_][1] = __builtin_amdgcn_mfma_f32_16x16x32_bf16(af, bfr2[1][ks], acc2[l_][1], 0, 0, 0);
    }
  }

  // epilogue: + cnt(l)*bias (float4); store transposed zb[n][c][l][w];
  // accumulate BN sum/sumsq on the stored (bf16-rounded) values.
  const int cbase = wv * 16 + quad * 4;
  float s1[4] = {0.f, 0.f, 0.f, 0.f}, s2[4] = {0.f, 0.f, 0.f, 0.f};
#pragma unroll
  for (int l_ = 0; l_ < 2; ++l_) {
    const int l = 2 * lb + l_;
    const float cnt = (float)(l + 1 < KS_ ? l + 1 : KS_);
#pragma unroll
    for (int nt = 0; nt < 2; ++nt) {
      const int w = nt * 16 + m16;
      if (w < V_) {
        f32x4 bias = *(const f32x4*)(biastab + w * 64 + cbase);
#pragma unroll
        for (int r = 0; r < 4; ++r) {
          ushort_t pv = f2b(acc2[l_][nt][r] + cnt * bias[r]);
          float zr = b2f(pv);
          s1[r] += zr; s2[r] += zr * zr;
          zb[((long)((n * 64 + cbase + r) * L_) + l) * V_ + w] = pv;
        }
      }
    }
  }
  // in-quad reduction over m16 (lanes of a quad share channels cbase..cbase+3)
#pragma unroll
  for (int off = 1; off < 16; off <<= 1) {
#pragma unroll
    for (int r = 0; r < 4; ++r) {
      s1[r] += __shfl_xor(s1[r], off, 64);
      s2[r] += __shfl_xor(s2[r], off, 64);
    }
  }
  if (m16 == 0) {
    float* sb = statsbuf + ((n * 512 + lb) & (NREP - 1)) * 128;
#pragma unroll
    for (int r = 0; r < 4; ++r) {
      atomicAdd(&sb[cbase + r], s1[r]);
      atomicAdd(&sb[64 + cbase + r], s2[r]);
    }
  }
}

// ---------------------------------------------------------------------------
// kapply: reduce statsbuf copies -> mean/var, then pure streaming
// out[i] = relu(relu(z[i]*sc[c]+sh[c]) + x[i]) with zb/x/out in the SAME
// flat [n][c][l][v] layout.  16 elems/thread, c uniform per group.
__global__ __launch_bounds__(256) void kapply(
    const ushort_t* __restrict__ zb, const float* __restrict__ x,
    const float* __restrict__ statsbuf,
    const float* __restrict__ gamma, const float* __restrict__ beta,
    float* __restrict__ out)
{
  const int tid = threadIdx.x;
  __shared__ float red[4][64][2];
  __shared__ float sc[64], sh[64];
  // reduce the NREP stats copies (64-KB L2-hot region)
  {
    const int c = tid & 63, grp = tid >> 6;       // 4 groups x 64 channels
    float a = 0.f, b = 0.f;
    for (int k = grp; k < NREP; k += 4) {
      a += statsbuf[k * 128 + c];
      b += statsbuf[k * 128 + 64 + c];
    }
    red[grp][c][0] = a;
    red[grp][c][1] = b;
  }
  __syncthreads();
  if (tid < 64) {
    const float inv = 1.0f / NLV;
    float s  = red[0][tid][0] + red[1][tid][0] + red[2][tid][0] + red[3][tid][0];
    float sq = red[0][tid][1] + red[1][tid][1] + red[2][tid][1] + red[3][tid][1];
    float mean = s * inv;
    float var  = sq * inv - mean * mean;
    float rstd = rsqrtf(var + 1e-5f);
    float g = gamma[tid];
    sc[tid] = rstd * g;
    sh[tid] = beta[tid] - mean * rstd * g;
  }
  __syncthreads();
  // streaming: 16 consecutive elems per thread (25600 % 16 == 0 -> c uniform)
  const long base = ((long)blockIdx.x * 256 + tid) * 16;
  const int c = (int)((base / 25600) & 63);
  const float scc = sc[c], shc = sh[c];
#pragma unroll
  for (int h = 0; h < 2; ++h) {
    us8 zp = *(const us8*)(zb + base + h * 8);
    f32x4 xa = *(const f32x4*)(x + base + h * 8);
    f32x4 xb = *(const f32x4*)(x + base + h * 8 + 4);
    f32x4 oa, ob;
#pragma unroll
    for (int j = 0; j < 4; ++j) {
      oa[j] = fmaxf(fmaxf(b2f(zp[j]) * scc + shc, 0.f) + xa[j], 0.f);
      ob[j] = fmaxf(fmaxf(b2f(zp[4 + j]) * scc + shc, 0.f) + xb[j], 0.f);
    }
    *(f32x4*)(out + base + h * 8) = oa;
    *(f32x4*)(out + base + h * 8 + 4) = ob;
  }
}

// ---------------------------------------------------------------------------
extern "C" void kernel_launch(void* const* d_in, const int* in_sizes, int n_in,
                              void* d_out, int out_size, void* d_ws, size_t ws_size,
                              hipStream_t stream)
{
  const float* x     = (const float*)d_in[0];
  const float* A     = (const float*)d_in[1];
  const float* E     = (const float*)d_in[2];
  const float* W     = (const float*)d_in[3];
  const float* cb    = (const float*)d_in[4];
  const float* gamma = (const float*)d_in[5];
  const float* beta  = (const float*)d_in[6];
  float* out = (float*)d_out;

  char* ws = (char*)d_ws;
  const size_t XS_OFF   = 0;                       // 13,107,200 B (bf16 xs, [n][l][1600])
  const size_t ZB_OFF   = 13107200;                // 13,107,200 B (bf16 zb, [n][c][l][w])
  const size_t WB_OFF   = 26214400;                // 24,576 B (bf16 Wb)
  const size_t A2_OFF   = WB_OFF + 32768;          // 6,144 B
  const size_t BIAS_OFF = A2_OFF + 16384;          // 8,192 B
  const size_t STAT_OFF = BIAS_OFF + 16384;        // 65,536 B (128 copies x 128 f32)
  ushort_t* xs      = (ushort_t*)(ws + XS_OFF);
  ushort_t* zb      = (ushort_t*)(ws + ZB_OFF);
  ushort_t* wb      = (ushort_t*)(ws + WB_OFF);
  ushort_t* a2      = (ushort_t*)(ws + A2_OFF);
  float*    biastab = (float*)(ws + BIAS_OFF);
  float*    statsbuf= (float*)(ws + STAT_OFF);

  kwin  <<<dim3(129, N_), 256, 0, stream>>>(x, xs, A, E, cb, W, a2, biastab, wb, statsbuf);
  kmain <<<dim3(512, N_), 256, 0, stream>>>(xs, wb, a2, biastab, zb, statsbuf);
  kapply<<<1600, 256, 0, stream>>>(zb, x, statsbuf, gamma, beta, out);
}

// Round 9
// 136.176 us; speedup vs baseline: 1.0144x; 1.0144x over previous
//
#include <hip/hip_runtime.h>

// ST-GCN fused block for MI355X (gfx950).  FP32 I/O, bf16 at MFMA boundaries.
// 3 dispatches: kwin(+prep) -> kmain(4-l blocks, dual-T1, 2 barriers; BN-stats
//               via 128-way replicated atomics) -> kapply(reduce+BN+ReLU+res).
// xs layout: [n][l][25 v][64 ci] bf16.   zb layout: [n][l][w][c] bf16.
// statsbuf: 128 copies x 128 f32 -> 8 atomics/address.

typedef unsigned short ushort_t;
typedef __attribute__((ext_vector_type(8))) short short8;   // 8 x bf16 MFMA frag
typedef __attribute__((ext_vector_type(4))) float f32x4;
typedef __attribute__((ext_vector_type(4))) unsigned short us4;
typedef __attribute__((ext_vector_type(8))) unsigned short us8;

#define N_  4
#define CI_ 64
#define CO_ 64
#define L_  1024
#define V_  25
#define P_  3
#define KS_ 9
#define NLV 102400.0f   // N_*L_*V_  (BN population count per channel)
#define NREP 128        // stats replication factor

__device__ __forceinline__ float b2f(ushort_t u) {
  union { float f; unsigned int i; } c; c.i = ((unsigned int)u) << 16; return c.f;
}
__device__ __forceinline__ ushort_t f2b(float f) {
  union { float f; unsigned int i; } c; c.f = f;
  unsigned int u = c.i;
  u += 0x7fffu + ((u >> 16) & 1u);      // round-to-nearest-even
  return (ushort_t)(u >> 16);
}

// ---------------------------------------------------------------------------
// kwin: causal 9-wide window-sum along l, fp32 x -> bf16 xs[n][l][25*64].
// block = (chunk of 8 l's, n); chunk==128 & n==0 does prep instead.
__global__ __launch_bounds__(256) void kwin(
    const float* __restrict__ x, ushort_t* __restrict__ xs,
    const float* __restrict__ A, const float* __restrict__ E,
    const float* __restrict__ cb, const float* __restrict__ W,
    ushort_t* __restrict__ a2raw, float* __restrict__ biastab,
    ushort_t* __restrict__ wb, float* __restrict__ statsbuf)
{
  const int chunk = blockIdx.x;                 // 0..128
  const int n = blockIdx.y;
  const int tid = threadIdx.x;

  if (chunk == 128) {                           // ---- prep block ----
    if (n != 0) return;
    __shared__ float colA[P_ * 32];
    if (tid < P_ * 32) {
      int p = tid >> 5, w = tid & 31;
      float s = 0.f;
      if (w < V_)
        for (int v = 0; v < V_; ++v) {
          int idx = (p * V_ + v) * V_ + w;
          s += A[idx] * E[idx];
        }
      colA[tid] = s;
    }
    for (int e = tid; e < 32 * 96; e += 256) {
      int w = e / 96, k = e - w * 96;
      int p = k >> 5, v = k & 31;
      float val = 0.f;
      if (w < V_ && v < V_) {
        int idx = (p * V_ + v) * V_ + w;
        val = A[idx] * E[idx];
      }
      a2raw[e] = f2b(val);
    }
    for (int e = tid; e < 192 * 64; e += 256) wb[e] = f2b(W[e]);
    __syncthreads();
    for (int e = tid; e < 32 * 64; e += 256) {
      int w = e >> 6, c = e & 63;
      float s = 0.f;
      for (int p = 0; p < P_; ++p) s += cb[p * 64 + c] * colA[p * 32 + w];
      biastab[e] = s;
    }
    for (int e = tid; e < NREP * 128; e += 256) statsbuf[e] = 0.f;
    return;
  }

  // ---- window block ----
  __shared__ ushort_t tile[64 * 402];           // 51.5 KB; stride 402 (odd dword)
  const int l0 = chunk * 8;
  const long xn = (long)n * CI_ * L_ * V_;
  for (int m = tid; m < 6400; m += 256) {       // 64 ci x 400 f32 -> bf16
    int ci = m / 100;
    int j4 = (m - ci * 100) * 4;                // 0..396
    f32x4 d;
    if (chunk == 0 && j4 < 200) {
      d = (f32x4){0.f, 0.f, 0.f, 0.f};          // l < 0 halo (li 0..7)
    } else {
      d = *(const f32x4*)(x + xn + (long)ci * (L_ * V_) + (l0 - 8) * V_ + j4);
    }
    ushort_t* dst = &tile[ci * 402 + j4];
    dst[0] = f2b(d[0]); dst[1] = f2b(d[1]); dst[2] = f2b(d[2]); dst[3] = f2b(d[3]);
  }
  __syncthreads();
  // sliding window per (v,ci) column; coalesced b16 stores per l_.
  const long xsbase = ((long)n * L_ + l0) * 1600;
  for (int cid = tid; cid < 1600; cid += 256) {
    const int v = cid >> 6, ci = cid & 63;
    const ushort_t* col = &tile[ci * 402 + v];  // + li*25 steps along l
    float s = 0.f;
#pragma unroll
    for (int li = 0; li < 9; ++li) s += b2f(col[li * 25]);
    xs[xsbase + cid] = f2b(s);                  // l_ = 0 (li window 0..8)
#pragma unroll
    for (int l_ = 1; l_ < 8; ++l_) {
      s += b2f(col[(l_ + 8) * 25]) - b2f(col[(l_ - 1) * 25]);
      xs[xsbase + l_ * 1600 + cid] = f2b(s);
    }
  }
}

// ---------------------------------------------------------------------------
// kmain: per-(n, 4 l's) block, 2 barriers total.
//   stage1 (2 passes, dual T1): t1 = Wb[192x64] @ Xs[64 x 64cols] per l-pair
//   stage2: z[c=64][w=32] per l = T1c[64x96] @ A2[96x32]; + cnt(l)*bias
//   epilogue: us4 zb stores + BN stats atomics into statsbuf copy.
__global__ __launch_bounds__(256) void kmain(
    const ushort_t* __restrict__ xs,      // [n][l][1600] bf16
    const ushort_t* __restrict__ Wb,      // [192][64] bf16 (L1-hot)
    const ushort_t* __restrict__ a2,      // [32 w][96 k] bf16 (L1-hot)
    const float*    __restrict__ biastab, // [32 w][64 c] f32 (L1-hot)
    ushort_t*       __restrict__ zb,
    float*          __restrict__ statsbuf)
{
  const int lb = blockIdx.x;            // 4 l's per block (0..255)
  const int n  = blockIdx.y;
  const int tid = threadIdx.x, lane = tid & 63, wv = tid >> 6;
  const int m16 = lane & 15, quad = lane >> 4;

  __shared__ __align__(16) ushort_t XT[4 * 2304];    // [l_][v][72ci]  18.4 KB
  __shared__ __align__(16) ushort_t T1[2 * 13312];   // [pair][l_][c][104]  53.2 KB

  // stage XT: 6400 contiguous bf16 -> 800 us8 chunks; zero pad rows v=25..31
  {
    const ushort_t* src = xs + ((long)n * L_ + 4 * lb) * 1600;
    for (int m = tid; m < 800; m += 256) {
      int l_ = m / 200, mr = m - l_ * 200;
      int v = mr >> 3, sub = mr & 7;
      *(us8*)(&XT[l_ * 2304 + v * 72 + sub * 8]) = *(const us8*)(src + m * 8);
    }
    if (tid < 252) {                    // 4 l_ x 63 us8 = pad rows 25..31
      int l_ = tid / 63, j = tid - l_ * 63;
      *(us8*)(&XT[l_ * 2304 + 1800 + j * 8]) = (us8){0,0,0,0,0,0,0,0};
    }
  }
  __syncthreads();

  // hoist Wb A-frags once (reused by both stage-1 passes)
  short8 af[3][2];
#pragma unroll
  for (int i = 0; i < 3; ++i) {
    const ushort_t* wrow = Wb + ((wv * 3 + i) * 16 + m16) * 64 + quad * 8;
    af[i][0] = *(const short8*)(wrow);
    af[i][1] = *(const short8*)(wrow + 32);
  }

  // ---- stage 1: two passes (l01 -> T1[0], l23 -> T1[1]); 24 MFMA each ----
#pragma unroll
  for (int pair = 0; pair < 2; ++pair) {
    short8 bfr[4][2];
#pragma unroll
    for (int nt = 0; nt < 4; ++nt)
#pragma unroll
      for (int ks = 0; ks < 2; ++ks)
        bfr[nt][ks] = *(const short8*)(
            &XT[(pair * 2 + (nt >> 1)) * 2304 + ((nt & 1) * 16 + m16) * 72 + ks * 32 + quad * 8]);

    f32x4 acc1[3][4];
#pragma unroll
    for (int i = 0; i < 3; ++i)
#pragma unroll
      for (int j = 0; j < 4; ++j) acc1[i][j] = (f32x4){0.f, 0.f, 0.f, 0.f};

#pragma unroll
    for (int i = 0; i < 3; ++i)
#pragma unroll
      for (int nt = 0; nt < 4; ++nt) {
        acc1[i][nt] = __builtin_amdgcn_mfma_f32_16x16x32_bf16(af[i][0], bfr[nt][0], acc1[i][nt], 0, 0, 0);
        acc1[i][nt] = __builtin_amdgcn_mfma_f32_16x16x32_bf16(af[i][1], bfr[nt][1], acc1[i][nt], 0, 0, 0);
      }
    // repack t1 -> T1[pair][l_][c][p*32+v]  (D: row = quad*4+r, col = m16)
#pragma unroll
    for (int i = 0; i < 3; ++i) {
      const int mt = wv * 3 + i;
#pragma unroll
      for (int nt = 0; nt < 4; ++nt) {
        const int l_ = nt >> 1;
        const int col = (nt & 1) * 16 + m16;
#pragma unroll
        for (int r = 0; r < 4; ++r) {
          int k = mt * 16 + quad * 4 + r;        // k = p*64 + c
          T1[pair * 13312 + l_ * 6656 + (k & 63) * 104 + (k >> 6) * 32 + col] = f2b(acc1[i][nt][r]);
        }
      }
    }
  }
  __syncthreads();

  // ---- stage 2: 12 MFMA per pair; a2 B-frags loaded once (global, L1-hot) ----
  short8 bfr2[2][3];
#pragma unroll
  for (int nt = 0; nt < 2; ++nt)
#pragma unroll
    for (int ks = 0; ks < 3; ++ks)
      bfr2[nt][ks] = *(const short8*)(a2 + (nt * 16 + m16) * 96 + ks * 32 + quad * 8);

  const int cbase = wv * 16 + quad * 4;
  float s1[4] = {0.f, 0.f, 0.f, 0.f}, s2[4] = {0.f, 0.f, 0.f, 0.f};
#pragma unroll
  for (int pair = 0; pair < 2; ++pair) {
    f32x4 acc2[2][2];
#pragma unroll
    for (int l_ = 0; l_ < 2; ++l_)
#pragma unroll
      for (int nt = 0; nt < 2; ++nt) acc2[l_][nt] = (f32x4){0.f, 0.f, 0.f, 0.f};

#pragma unroll
    for (int l_ = 0; l_ < 2; ++l_)
#pragma unroll
      for (int ks = 0; ks < 3; ++ks) {
        short8 afT = *(const short8*)(&T1[pair * 13312 + l_ * 6656 + (wv * 16 + m16) * 104 + ks * 32 + quad * 8]);
        acc2[l_][0] = __builtin_amdgcn_mfma_f32_16x16x32_bf16(afT, bfr2[0][ks], acc2[l_][0], 0, 0, 0);
        acc2[l_][1] = __builtin_amdgcn_mfma_f32_16x16x32_bf16(afT, bfr2[1][ks], acc2[l_][1], 0, 0, 0);
      }

    // epilogue: + cnt(l)*bias (float4), us4 store; accumulate BN stats
#pragma unroll
    for (int l_ = 0; l_ < 2; ++l_) {
      const int l = 4 * lb + pair * 2 + l_;
      const float cnt = (float)(l + 1 < KS_ ? l + 1 : KS_);
#pragma unroll
      for (int nt = 0; nt < 2; ++nt) {
        const int w = nt * 16 + m16;
        if (w < V_) {
          f32x4 bias = *(const f32x4*)(biastab + w * 64 + cbase);
          us4 pack;
#pragma unroll
          for (int r = 0; r < 4; ++r) {
            pack[r] = f2b(acc2[l_][nt][r] + cnt * bias[r]);
            float zr = b2f(pack[r]);            // stats on the stored value
            s1[r] += zr; s2[r] += zr * zr;
          }
          *(us4*)(&zb[(((long)(n * L_ + l) * V_ + w) << 6) + cbase]) = pack;
        }
      }
    }
  }
  // in-quad reduction over m16 (lanes of a quad share channels cbase..cbase+3)
#pragma unroll
  for (int off = 1; off < 16; off <<= 1) {
#pragma unroll
    for (int r = 0; r < 4; ++r) {
      s1[r] += __shfl_xor(s1[r], off, 64);
      s2[r] += __shfl_xor(s2[r], off, 64);
    }
  }
  if (m16 == 0) {
    float* sb = statsbuf + ((n * 256 + lb) & (NREP - 1)) * 128;
#pragma unroll
    for (int r = 0; r < 4; ++r) {
      atomicAdd(&sb[cbase + r], s1[r]);
      atomicAdd(&sb[64 + cbase + r], s2[r]);
    }
  }
}

// ---------------------------------------------------------------------------
// kapply: reduce statsbuf copies -> mean/var, then
// out[n,c,l,v] = relu(relu((z-mean)*rstd*g+b) + x).  4 l's per block.
__global__ __launch_bounds__(256) void kapply(
    const ushort_t* __restrict__ zb, const float* __restrict__ x,
    const float* __restrict__ statsbuf,
    const float* __restrict__ gamma, const float* __restrict__ beta,
    float* __restrict__ out)
{
  const int n = blockIdx.y, chunk = blockIdx.x;   // 4 l's per block
  const int tid = threadIdx.x;
  __shared__ ushort_t zl[100 * 66];               // 13.2 KB
  __shared__ float red[4][64][2];
  __shared__ float sc[64], sh[64];
  const long zbase = (long)((n * L_ + chunk * 4) * V_) * 64;   // 6400 elems
  for (int m = tid; m < 3200; m += 256) {         // u32 = 2 bf16
    int rr = m >> 5, c2 = (m & 31) * 2;
    *(unsigned int*)(&zl[rr * 66 + c2]) = ((const unsigned int*)(zb + zbase))[m];
  }
  // reduce the NREP stats copies (64-KB L2-hot region)
  {
    const int c = tid & 63, grp = tid >> 6;       // 4 groups x 64 channels
    float a = 0.f, b = 0.f;
    for (int k = grp; k < NREP; k += 4) {
      a += statsbuf[k * 128 + c];
      b += statsbuf[k * 128 + 64 + c];
    }
    red[grp][c][0] = a;
    red[grp][c][1] = b;
  }
  __syncthreads();
  if (tid < 64) {
    const float inv = 1.0f / NLV;
    float s  = red[0][tid][0] + red[1][tid][0] + red[2][tid][0] + red[3][tid][0];
    float sq = red[0][tid][1] + red[1][tid][1] + red[2][tid][1] + red[3][tid][1];
    float mean = s * inv;
    float var  = sq * inv - mean * mean;
    float rstd = rsqrtf(var + 1e-5f);
    float g = gamma[tid];
    sc[tid] = rstd * g;
    sh[tid] = beta[tid] - mean * rstd * g;
  }
  __syncthreads();
  for (int e = tid; e < 6400; e += 256) {
    int c = e / 100, rr = e - c * 100;            // rr = l*25+v within chunk
    float z = b2f(zl[rr * 66 + c]);
    float y = fmaxf(z * sc[c] + sh[c], 0.f);
    long xi = ((long)(n * 64 + c) * L_ + chunk * 4) * V_ + rr;
    float o = fmaxf(y + x[xi], 0.f);
    out[xi] = o;
  }
}

// ---------------------------------------------------------------------------
extern "C" void kernel_launch(void* const* d_in, const int* in_sizes, int n_in,
                              void* d_out, int out_size, void* d_ws, size_t ws_size,
                              hipStream_t stream)
{
  const float* x     = (const float*)d_in[0];
  const float* A     = (const float*)d_in[1];
  const float* E     = (const float*)d_in[2];
  const float* W     = (const float*)d_in[3];
  const float* cb    = (const float*)d_in[4];
  const float* gamma = (const float*)d_in[5];
  const float* beta  = (const float*)d_in[6];
  float* out = (float*)d_out;

  char* ws = (char*)d_ws;
  const size_t XS_OFF   = 0;                       // 13,107,200 B (bf16 xs, [n][l][1600])
  const size_t ZB_OFF   = 13107200;                // 13,107,200 B (bf16 zb, [n][l][w][c])
  const size_t WB_OFF   = 26214400;                // 24,576 B (bf16 Wb)
  const size_t A2_OFF   = WB_OFF + 32768;          // 6,144 B
  const size_t BIAS_OFF = A2_OFF + 16384;          // 8,192 B
  const size_t STAT_OFF = BIAS_OFF + 16384;        // 65,536 B (128 copies x 128 f32)
  ushort_t* xs      = (ushort_t*)(ws + XS_OFF);
  ushort_t* zb      = (ushort_t*)(ws + ZB_OFF);
  ushort_t* wb      = (ushort_t*)(ws + WB_OFF);
  ushort_t* a2      = (ushort_t*)(ws + A2_OFF);
  float*    biastab = (float*)(ws + BIAS_OFF);
  float*    statsbuf= (float*)(ws + STAT_OFF);

  kwin  <<<dim3(129, N_), 256, 0, stream>>>(x, xs, A, E, cb, W, a2, biastab, wb, statsbuf);
  kmain <<<dim3(256, N_), 256, 0, stream>>>(xs, wb, a2, biastab, zb, statsbuf);
  kapply<<<dim3(256, N_), 256, 0, stream>>>(zb, x, statsbuf, gamma, beta, out);
}